// Round 6
// baseline (389.180 us; speedup 1.0000x reference)
//
#include <hip/hip_runtime.h>

// HQQ 4-bit dequant + linear (Llama-7B up-proj, decode: 8 tokens)
// OUT=11008, IN=4096, GS=64, G=704512, OC=172 (=G/IN; OUT=64*OC)
// W_q: [32, G] int32 (one byte per word: hi nibble -> unpacked row rq,
//      lo nibble -> row rq+32 of the [64, G] tensor)
// Mapping: W_r[o, i] with r=o/172, oc=o%172, g=oc*4096+i.
//
// R9 theory: R8 (1-wave, no LDS x) regressed -> R5's 4-wave block with
// LDS-shared x is the right anatomy; its remaining loss is one-shot blocks
// (loads in flight ~45% of block lifetime). R9 = R5 anatomy + 2-step
// pipeline per block:
//  - block owns (bx, ks) and TWO consecutive oc; x staged once (kbase
//    depends only on ks), reused across both steps.
//  - step-1 Wq loads issue at the top of step-0 compute -> cold stream in
//    flight through compute; compiler's per-register waits drain them.
//  - ZERO barriers after prologue: s/z per-iter regs from L2 (per-lane
//    data); cross-lane reduce is per-wave 8-row LDS transpose (2 KB/wave,
//    same-wave ds ordering = lgkmcnt only, no s_barrier) + 3 shfl_xor.
//  - prologue: 8 x-DMA, fence, 8 Wq, "vmcnt(8); s_barrier" (drains exactly
//    the DMA; Wq rides through the barrier).
// LDS 40 KB -> 4 blocks/CU; VGPR ~124 under (256,4). Grid 1376 XCD-chunked
// (172 tasks/XCD, bx-quads intact since 172%4==0).

#define OUT_ 11008
#define IN_ 4096
#define G_ 704512
#define OC_ 172
#define KS 4
#define KC (IN_ / KS)       // 1024
#define ITERS (KC / 256)    // 4
#define STEPS 2
#define NCHUNK (OC_ * KS)   // 688 (oc,ks) chunks
#define NB (NCHUNK * 4 / STEPS)  // 1376 blocks: 4 bx x 4 ks x 86 ocg

typedef const __attribute__((address_space(1))) void* gptr1_t;
typedef __attribute__((address_space(3))) void* sptr3_t;

__device__ __forceinline__ void gload_lds16(const float* g, float* l) {
    // dest is wave-uniform; HW adds lane*16B. src is per-lane.
    __builtin_amdgcn_global_load_lds((gptr1_t)g, (sptr3_t)l, 16, 0, 0);
}

__global__ __launch_bounds__(256, 4)
void hqq_gemv(const int* __restrict__ Wq, const float* __restrict__ scale,
              const float* __restrict__ zero, const float* __restrict__ x,
              float* __restrict__ ws) {
    __shared__ float x_lds[8 * KC];     // 32 KB, staged once, read-only after
    __shared__ float red_lds[4 * 512];  // 8 KB: 2 KB per wave, wave-local

    const int lane = threadIdx.x;              // 0..63
    const int ty   = threadIdx.y;              // 0..3
    const int bid  = blockIdx.x;
    const int xcd  = bid & 7;                  // HW round-robin XCD
    const int t    = xcd * (NB / 8) + (bid >> 3);  // 0..1375, XCD-chunked
    const int bx   = t & 3;                    // rq-group (8 packed rows)
    const int ks   = (t >> 2) & 3;             // K-split
    const int ocg  = t >> 4;                   // 0..85 (pair of oc)
    const int rq0  = bx * 8 + ty * 2;          // packed rows rq0, rq0+1

    const int kbase = ks * KC;

    // ---- prologue: 8 x-DMA (valid for BOTH oc-steps), fence, 8 Wq ----
#pragma unroll
    for (int r = 0; r < 8; ++r)                // token b = r
        gload_lds16(x + r * IN_ + kbase + ty * 256 + lane * 4,
                    x_lds + r * KC + ty * 256);
    asm volatile("" ::: "memory");             // keep DMA oldest in FIFO

    const int* __restrict__ wqA = Wq + (long)rq0 * G_ +
                                  (ocg * STEPS) * IN_ + kbase + lane * 4;
    const int* __restrict__ wqB = wqA + G_;
    int4 qa[STEPS][ITERS], qb[STEPS][ITERS];
#pragma unroll
    for (int it = 0; it < ITERS; ++it) {
        qa[0][it] = *(const int4*)(wqA + it * 256);
        qb[0][it] = *(const int4*)(wqB + it * 256);
    }
    // drain exactly the 8 DMA (oldest, FIFO); Wq stays in flight.
    asm volatile("s_waitcnt vmcnt(8)\n\ts_barrier" ::: "memory");

    float* const red = red_lds + ty * 512;     // this wave's 8x64 region

#pragma unroll
    for (int s = 0; s < STEPS; ++s) {
        if (s + 1 < STEPS) {                   // next step's Wq: issue NOW,
#pragma unroll                                 // drains under this compute
            for (int it = 0; it < ITERS; ++it) {
                qa[s + 1][it] = *(const int4*)(wqA + (s + 1) * IN_ + it * 256);
                qb[s + 1][it] = *(const int4*)(wqB + (s + 1) * IN_ + it * 256);
            }
        }
        const int oc = ocg * STEPS + s;
        const int gb = oc * IN_ + kbase;

        // acc[0]=hi(rq0) acc[1]=lo(rq0) acc[2]=hi(rq0+1) acc[3]=lo(rq0+1)
        float acc[4][8];
#pragma unroll
        for (int r = 0; r < 4; ++r)
#pragma unroll
            for (int b = 0; b < 8; ++b) acc[r][b] = 0.f;

#pragma unroll
        for (int it = 0; it < ITERS; ++it) {
            const int i = it * 256 + lane * 4;
            const float4 s4 = *(const float4*)(scale + gb + i);  // L2 (bx-sibs share)
            const float4 z4 = *(const float4*)(zero + gb + i);
            const float ss[4] = {s4.x, s4.y, s4.z, s4.w};
            const float zs[4] = {-z4.x * s4.x, -z4.y * s4.y,
                                 -z4.z * s4.z, -z4.w * s4.w};
            const int qsA[4] = {qa[s][it].x, qa[s][it].y, qa[s][it].z, qa[s][it].w};
            const int qsB[4] = {qb[s][it].x, qb[s][it].y, qb[s][it].z, qb[s][it].w};

            float w[4][4];  // [hiA, loA, hiB, loB][j]
#pragma unroll
            for (int j = 0; j < 4; ++j) {
                w[0][j] = fmaf((float)((qsA[j] >> 4) & 0xF), ss[j], zs[j]);
                w[1][j] = fmaf((float)( qsA[j]       & 0xF), ss[j], zs[j]);
                w[2][j] = fmaf((float)((qsB[j] >> 4) & 0xF), ss[j], zs[j]);
                w[3][j] = fmaf((float)( qsB[j]       & 0xF), ss[j], zs[j]);
            }
#pragma unroll
            for (int b = 0; b < 8; ++b) {
                const float4 xb = *(const float4*)(x_lds + b * KC + i);
#pragma unroll
                for (int r = 0; r < 4; ++r) {
                    float a = acc[r][b];
                    a = fmaf(xb.x, w[r][0], a);
                    a = fmaf(xb.y, w[r][1], a);
                    a = fmaf(xb.z, w[r][2], a);
                    a = fmaf(xb.w, w[r][3], a);
                    acc[r][b] = a;
                }
            }
        }

        // ---- per-wave transpose reduce: NO barrier (same-wave ds order) ----
        // 4 rounds; round m: write rows o=b (cols lane^(b<<2): permutation,
        // conflict-free), read row lane>>3 logical cols (lane&7)*8..+7,
        // 3-level shfl_xor over the 8 col-octet lanes.
#pragma unroll
        for (int m = 0; m < 4; ++m) {
#pragma unroll
            for (int b = 0; b < 8; ++b)
                red[b * 64 + (lane ^ (b << 2))] = acc[m][b];
            const int ro = lane >> 3;
            const int c0 = (lane & 7) * 8;
            const float4 u0 = *(const float4*)(red + ro * 64 + ((c0    ) ^ (ro << 2)));
            const float4 u1 = *(const float4*)(red + ro * 64 + ((c0 + 4) ^ (ro << 2)));
            float v = ((u0.x + u0.y) + (u0.z + u0.w)) +
                      ((u1.x + u1.y) + (u1.z + u1.w));
            v += __shfl_xor(v, 1, 64);
            v += __shfl_xor(v, 2, 64);
            v += __shfl_xor(v, 4, 64);
            if ((lane & 7) == 0)               // 8 lanes -> 32 B coalesced
                ws[(((bx * OC_ + oc) * KS + ks) << 7) + ty * 32 + m * 8 + ro] = v;
        }
    }
}

__global__ void hqq_reduce(const float* __restrict__ ws,
                           const float* __restrict__ bias,
                           float* __restrict__ out) {
    // thread t = ws slot (c, o): reads coalesced, scatter on the store side.
    const int t = blockIdx.x * 256 + threadIdx.x;  // 0 .. 688*128-1 = 88063
    if (t >= NCHUNK * 128) return;
    const int c = t >> 7;                      // chunk = bx*OC_ + oc, 0..687
    const int o = t & 127;                     // o = ty*32 + r*8 + b
    float v = 0.f;
#pragma unroll
    for (int k = 0; k < KS; ++k) v += ws[(c << 9) + (k << 7) + o];
    const int bx = c / OC_;
    const int oc = c % OC_;
    const int w_ = o >> 5;
    const int r  = (o >> 3) & 3;
    const int b  = o & 7;
    const int rq  = bx * 8 + w_ * 2 + (r >> 1);
    const int row = rq + ((r & 1) ? 32 : 0);
    const int oo  = row * OC_ + oc;
    out[b * OUT_ + oo] = v + bias[oo];
}

extern "C" void kernel_launch(void* const* d_in, const int* in_sizes, int n_in,
                              void* d_out, int out_size, void* d_ws, size_t ws_size,
                              hipStream_t stream) {
    const int*   Wq    = (const int*)d_in[0];    // [32, 704512] int32
    const float* scale = (const float*)d_in[1];  // [1, 704512]
    const float* zero  = (const float*)d_in[2];  // [1, 704512]
    const float* x     = (const float*)d_in[3];  // [8, 1, 4096]
    const float* bias  = (const float*)d_in[4];  // [11008]
    float* out = (float*)d_out;                  // [8, 1, 11008]
    float* ws  = (float*)d_ws;                   // 688*512 floats = 1.38 MB

    dim3 grid(NB);          // 1376 two-step blocks, XCD-chunked
    dim3 block(64, 4);
    hqq_gemv<<<grid, block, 0, stream>>>(Wq, scale, zero, x, ws);
    hqq_reduce<<<(NCHUNK * 128 + 255) / 256, 256, 0, stream>>>(ws, bias, out);
}

// Round 7
// 230.821 us; speedup vs baseline: 1.6861x; 1.6861x over previous
//
#include <hip/hip_runtime.h>

// HQQ 4-bit dequant + linear (Llama-7B up-proj, decode: 8 tokens)
// OUT=11008, IN=4096, GS=64, G=704512, OC=172 (=G/IN; OUT=64*OC)
// W_q: [32, G] int32 (one byte per word: hi nibble -> unpacked row rq,
//      lo nibble -> row rq+32 of the [64, G] tensor)
// Mapping: W_r[o, i] with r=o/172, oc=o%172, g=oc*4096+i.
//
// R10 theory: R9 spilled (VGPR_Count=64, 395 MB scratch writes) -> revert
// to R5's proven anatomy (4-wave block, DMA-staged LDS, __syncthreads,
// one-shot) and attack TLP instead: KS=8 halves every per-block quantum.
//  - Wq register buffer 32->16 VGPR, census ~95 -> __launch_bounds__(256,5)
//    (VGPR cap 102) -> 5 blocks/CU via 28 KB LDS: 20 waves/CU vs R5's 16.
//  - 5504 blocks: finer dispatch stagger, half the tail bubble.
//  - Tail: R9's correctness-proven per-wave transpose reduce (wave-local
//    2 KB red region, same-wave lgkmcnt ordering, no barrier).
//  - Prologue: R5 semantics exactly (DMA issue, Wq loads, __syncthreads).
//  - XCD chunking: 688 chunks/XCD; bx-quads intact (688%4==0) so the 4
//    bx-siblings sharing an s/z slice hit the same XCD L2.

#define OUT_ 11008
#define IN_ 4096
#define G_ 704512
#define OC_ 172
#define KS 8
#define KC (IN_ / KS)       // 512
#define ITERS (KC / 256)    // 2
#define NCHUNK (OC_ * KS)   // 1376 (oc,ks) chunks
#define NB (NCHUNK * 4)     // 5504 blocks (x4 bx); 5504/8 = 688 per XCD

typedef const __attribute__((address_space(1))) void* gptr1_t;
typedef __attribute__((address_space(3))) void* sptr3_t;

__device__ __forceinline__ void gload_lds16(const float* g, float* l) {
    // dest is wave-uniform; HW adds lane*16B. src is per-lane.
    __builtin_amdgcn_global_load_lds((gptr1_t)g, (sptr3_t)l, 16, 0, 0);
}

__global__ __launch_bounds__(256, 5)
void hqq_gemv(const int* __restrict__ Wq, const float* __restrict__ scale,
              const float* __restrict__ zero, const float* __restrict__ x,
              float* __restrict__ ws) {
    __shared__ float x_lds[8 * KC];     // 16 KB
    __shared__ float s_lds[KC];         // 2 KB
    __shared__ float z_lds[KC];         // 2 KB
    __shared__ float red_lds[4 * 512];  // 8 KB: 2 KB per wave, wave-local

    const int lane = threadIdx.x;              // 0..63
    const int ty   = threadIdx.y;              // 0..3
    const int bid  = blockIdx.x;
    const int xcd  = bid & 7;                  // HW round-robin XCD
    const int t    = xcd * (NB / 8) + (bid >> 3);  // 0..5503, XCD-chunked
    const int bx   = t & 3;                    // rq-group (8 packed rows)
    const int rest = t >> 2;                   // 0..1375
    const int ks   = rest & 7;                 // K-split
    const int oc   = rest >> 3;                // 0..171
    const int rq0  = bx * 8 + ty * 2;          // packed rows rq0, rq0+1

    const int kbase = ks * KC;
    const int gb    = oc * IN_ + kbase;

    // ---- stage x (16 KB), s (2 KB), z (2 KB) via LDS-DMA ----
    // wave ty stages tokens {2ty, 2ty+1}; wave 0 also s, wave 1 also z.
#pragma unroll
    for (int h = 0; h < 2; ++h) {
        const int r0 = ty * 2;
        gload_lds16(x + (r0    ) * IN_ + kbase + h * 256 + lane * 4,
                    x_lds + (r0    ) * KC + h * 256);
        gload_lds16(x + (r0 + 1) * IN_ + kbase + h * 256 + lane * 4,
                    x_lds + (r0 + 1) * KC + h * 256);
    }
    if (ty == 0) {
#pragma unroll
        for (int h = 0; h < 2; ++h)
            gload_lds16(scale + gb + h * 256 + lane * 4, s_lds + h * 256);
    } else if (ty == 1) {
#pragma unroll
        for (int h = 0; h < 2; ++h)
            gload_lds16(zero + gb + h * 256 + lane * 4, z_lds + h * 256);
    }

    // ---- prefetch ALL Wq for this wave: 4 independent dwordx4 (16 VGPR) ----
    const int* __restrict__ wqA = Wq + (long)rq0 * G_ + gb + lane * 4;
    const int* __restrict__ wqB = wqA + G_;
    int4 qa[ITERS], qb[ITERS];
#pragma unroll
    for (int it = 0; it < ITERS; ++it) {
        qa[it] = *(const int4*)(wqA + it * 256);
        qb[it] = *(const int4*)(wqB + it * 256);
    }

    __syncthreads();  // R5 semantics: drain DMA + Wq, all operands resident

    // acc[0]=hi(rq0) acc[1]=lo(rq0) acc[2]=hi(rq0+1) acc[3]=lo(rq0+1)
    float acc[4][8];
#pragma unroll
    for (int r = 0; r < 4; ++r)
#pragma unroll
        for (int b = 0; b < 8; ++b) acc[r][b] = 0.f;

#pragma unroll
    for (int it = 0; it < ITERS; ++it) {
        const int i = it * 256 + lane * 4;
        const float4 s4 = *(const float4*)(s_lds + i);
        const float4 z4 = *(const float4*)(z_lds + i);
        const float ss[4] = {s4.x, s4.y, s4.z, s4.w};
        const float zs[4] = {-z4.x * s4.x, -z4.y * s4.y, -z4.z * s4.z, -z4.w * s4.w};
        const int qsA[4] = {qa[it].x, qa[it].y, qa[it].z, qa[it].w};
        const int qsB[4] = {qb[it].x, qb[it].y, qb[it].z, qb[it].w};

        float w[4][4];  // [hiA, loA, hiB, loB][j]
#pragma unroll
        for (int j = 0; j < 4; ++j) {
            w[0][j] = fmaf((float)((qsA[j] >> 4) & 0xF), ss[j], zs[j]);
            w[1][j] = fmaf((float)( qsA[j]       & 0xF), ss[j], zs[j]);
            w[2][j] = fmaf((float)((qsB[j] >> 4) & 0xF), ss[j], zs[j]);
            w[3][j] = fmaf((float)( qsB[j]       & 0xF), ss[j], zs[j]);
        }
#pragma unroll
        for (int b = 0; b < 8; ++b) {
            const float4 xb = *(const float4*)(x_lds + b * KC + i);
#pragma unroll
            for (int r = 0; r < 4; ++r) {
                float a = acc[r][b];
                a = fmaf(xb.x, w[r][0], a);
                a = fmaf(xb.y, w[r][1], a);
                a = fmaf(xb.z, w[r][2], a);
                a = fmaf(xb.w, w[r][3], a);
                acc[r][b] = a;
            }
        }
    }

    // ---- per-wave transpose reduce: NO barrier (same-wave ds ordering) ----
    // round m: write rows b (col lane^(b<<2): permutation, conflict-free);
    // read row ro=lane>>3, col-octet (lane&7)*8; 3-level shfl_xor.
    float* const red = red_lds + ty * 512;     // this wave's 8x64 region
#pragma unroll
    for (int m = 0; m < 4; ++m) {
#pragma unroll
        for (int b = 0; b < 8; ++b)
            red[b * 64 + (lane ^ (b << 2))] = acc[m][b];
        const int ro = lane >> 3;
        const int c0 = (lane & 7) * 8;
        const float4 u0 = *(const float4*)(red + ro * 64 + ((c0    ) ^ (ro << 2)));
        const float4 u1 = *(const float4*)(red + ro * 64 + ((c0 + 4) ^ (ro << 2)));
        float v = ((u0.x + u0.y) + (u0.z + u0.w)) +
                  ((u1.x + u1.y) + (u1.z + u1.w));
        v += __shfl_xor(v, 1, 64);
        v += __shfl_xor(v, 2, 64);
        v += __shfl_xor(v, 4, 64);
        if ((lane & 7) == 0)                   // 8 lanes -> 32 B coalesced
            ws[(long)(((bx * OC_ + oc) * KS + ks) << 7) + ty * 32 + m * 8 + ro] = v;
    }
}

__global__ void hqq_reduce(const float* __restrict__ ws,
                           const float* __restrict__ bias,
                           float* __restrict__ out) {
    // thread t = ws slot (c, o): reads coalesced, scatter on the store side.
    const int t = blockIdx.x * 256 + threadIdx.x;  // 0 .. 688*128-1 = 88063
    if (t >= 688 * 128) return;
    const int c = t >> 7;                      // chunk = bx*OC_ + oc, 0..687
    const int o = t & 127;                     // o = ty*32 + m*8 + b
    float v = 0.f;
#pragma unroll
    for (int k = 0; k < KS; ++k) v += ws[((long)c << 10) + (k << 7) + o];
    const int bx = c / OC_;
    const int oc = c % OC_;
    const int w_ = o >> 5;
    const int m  = (o >> 3) & 3;
    const int b  = o & 7;
    const int rq  = bx * 8 + w_ * 2 + (m >> 1);
    const int row = rq + ((m & 1) ? 32 : 0);
    const int oo  = row * OC_ + oc;
    out[b * OUT_ + oo] = v + bias[oo];
}

extern "C" void kernel_launch(void* const* d_in, const int* in_sizes, int n_in,
                              void* d_out, int out_size, void* d_ws, size_t ws_size,
                              hipStream_t stream) {
    const int*   Wq    = (const int*)d_in[0];    // [32, 704512] int32
    const float* scale = (const float*)d_in[1];  // [1, 704512]
    const float* zero  = (const float*)d_in[2];  // [1, 704512]
    const float* x     = (const float*)d_in[3];  // [8, 1, 4096]
    const float* bias  = (const float*)d_in[4];  // [11008]
    float* out = (float*)d_out;                  // [8, 1, 11008]
    float* ws  = (float*)d_ws;                   // 688*8*128 floats = 2.75 MB

    dim3 grid(NB);          // 5504 blocks, XCD-chunked
    dim3 block(64, 4);
    hqq_gemv<<<grid, block, 0, stream>>>(Wq, scale, zero, x, ws);
    hqq_reduce<<<(688 * 128 + 255) / 256, 256, 0, stream>>>(ws, bias, out);
}

// Round 8
// 182.079 us; speedup vs baseline: 2.1374x; 1.2677x over previous
//
#include <hip/hip_runtime.h>

// HQQ 4-bit dequant + linear (Llama-7B up-proj, decode: 8 tokens)
// OUT=11008, IN=4096, GS=64, G=704512, OC=172 (=G/IN; OUT=64*OC)
// W_q: [32, G] int32 (one byte per word: hi nibble -> unpacked row rq,
//      lo nibble -> row rq+32 of the [64, G] tensor)
// Mapping: W_r[o, i] with r=o/172, oc=o%172, g=oc*4096+i.
//
// R11 theory: R5's gemv (~29 us) runs at ~53% of HBM BW because loads are
// in flight only ~50% of a block's lifetime (one-shot stage->drain->compute).
// R9's pipeline attempt was right structurally but spilled (64-VGPR Wq
// ping-pong at KS=4). At KS=8 the ping-pong halves to 32 VGPR -> fits under
// the never-spilled (256,4) bound. Block = (bx, ks, 4 consecutive oc):
//  - x DMA-staged once (16 KB), reused by all 4 steps.
//  - step s+1's 8 Wq loads issue before step s's compute -> cold stream in
//    flight ~87% of lifetime; compiler's per-register waits drain them.
//  - s/z read at use from L2 (4 bx-siblings share slice via XCD chunking).
//  - prologue: R5 semantics (DMA + Wq[0] + __syncthreads); no barriers after.
//  - tail: R10's proven per-wave transpose reduce (wave-local 2 KB, same-wave
//    lgkmcnt ordering) + R10's reduce kernel verbatim.
// LDS 24 KB, census ~120 VGPR -> 4 blocks/CU, 16 waves. Grid 1376 XCD-chunked
// (172/XCD; bx-quads intact: 172%4==0).

#define OUT_ 11008
#define IN_ 4096
#define G_ 704512
#define OC_ 172
#define KS 8
#define KC (IN_ / KS)       // 512
#define ITERS (KC / 256)    // 2
#define STEPS 4
#define OCG (OC_ / STEPS)   // 43 oc-groups
#define NB (4 * KS * OCG)   // 1376 blocks; 1376/8 = 172 per XCD

typedef const __attribute__((address_space(1))) void* gptr1_t;
typedef __attribute__((address_space(3))) void* sptr3_t;

__device__ __forceinline__ void gload_lds16(const float* g, float* l) {
    // dest is wave-uniform; HW adds lane*16B. src is per-lane.
    __builtin_amdgcn_global_load_lds((gptr1_t)g, (sptr3_t)l, 16, 0, 0);
}

__global__ __launch_bounds__(256, 4)
void hqq_gemv(const int* __restrict__ Wq, const float* __restrict__ scale,
              const float* __restrict__ zero, const float* __restrict__ x,
              float* __restrict__ ws) {
    __shared__ float x_lds[8 * KC];     // 16 KB, staged once
    __shared__ float red_lds[4 * 512];  // 8 KB: 2 KB per wave, wave-local

    const int lane = threadIdx.x;              // 0..63
    const int ty   = threadIdx.y;              // 0..3
    const int bid  = blockIdx.x;
    const int xcd  = bid & 7;                  // HW round-robin XCD
    const int idx  = xcd * (NB / 8) + (bid >> 3);  // 0..1375, XCD-chunked
    const int bx   = idx & 3;                  // rq-group (8 packed rows)
    const int rest = idx >> 2;                 // 0..343
    const int ks   = rest & 7;                 // K-split
    const int ocg  = rest >> 3;                // 0..42
    const int rq0  = bx * 8 + ty * 2;          // packed rows rq0, rq0+1

    const int kbase = ks * KC;

    // ---- stage x once via LDS-DMA: 4 rounds, wave ty covers 256 floats ----
#pragma unroll
    for (int r = 0; r < 4; ++r) {
        const int off = r * 1024 + ty * 256;   // [b][k] linear, b = off>>9
        const int b = off >> 9, k = off & (KC - 1);
        gload_lds16(x + b * IN_ + kbase + k + lane * 4, x_lds + off);
    }

    // ---- step-0 Wq: 4 independent dwordx4 (16 VGPR of the 32-reg pingpong)
    const int oc0 = ocg * STEPS;
    const int* __restrict__ wqA = Wq + (long)rq0 * G_ + (long)oc0 * IN_ +
                                  kbase + lane * 4;
    const int* __restrict__ wqB = wqA + G_;
    int4 qa[2][ITERS], qb[2][ITERS];           // ping-pong, static idx
#pragma unroll
    for (int it = 0; it < ITERS; ++it) {
        qa[0][it] = *(const int4*)(wqA + it * 256);
        qb[0][it] = *(const int4*)(wqB + it * 256);
    }

    __syncthreads();   // R5 semantics: drain x-DMA + step-0 Wq

    float* const red = red_lds + ty * 512;     // this wave's 8x64 region

#pragma unroll
    for (int s = 0; s < STEPS; ++s) {
        const int cur = s & 1, nxt = cur ^ 1;  // constants after unroll
        if (s + 1 < STEPS) {                   // next step's Wq: issue NOW,
#pragma unroll                                 // drains under this compute
            for (int it = 0; it < ITERS; ++it) {
                qa[nxt][it] = *(const int4*)(wqA + (s + 1) * IN_ + it * 256);
                qb[nxt][it] = *(const int4*)(wqB + (s + 1) * IN_ + it * 256);
            }
        }
        const int oc = oc0 + s;
        const int gb = oc * IN_ + kbase;

        // acc[0]=hi(rq0) acc[1]=lo(rq0) acc[2]=hi(rq0+1) acc[3]=lo(rq0+1)
        float acc[4][8];
#pragma unroll
        for (int r = 0; r < 4; ++r)
#pragma unroll
            for (int b = 0; b < 8; ++b) acc[r][b] = 0.f;

#pragma unroll
        for (int it = 0; it < ITERS; ++it) {
            const int i = it * 256 + lane * 4;
            const float4 s4 = *(const float4*)(scale + gb + i);  // L2: bx-sibs share
            const float4 z4 = *(const float4*)(zero + gb + i);
            const float ss[4] = {s4.x, s4.y, s4.z, s4.w};
            const float zs[4] = {-z4.x * s4.x, -z4.y * s4.y,
                                 -z4.z * s4.z, -z4.w * s4.w};
            const int qsA[4] = {qa[cur][it].x, qa[cur][it].y,
                                qa[cur][it].z, qa[cur][it].w};
            const int qsB[4] = {qb[cur][it].x, qb[cur][it].y,
                                qb[cur][it].z, qb[cur][it].w};

            float w[4][4];  // [hiA, loA, hiB, loB][j]
#pragma unroll
            for (int j = 0; j < 4; ++j) {
                w[0][j] = fmaf((float)((qsA[j] >> 4) & 0xF), ss[j], zs[j]);
                w[1][j] = fmaf((float)( qsA[j]       & 0xF), ss[j], zs[j]);
                w[2][j] = fmaf((float)((qsB[j] >> 4) & 0xF), ss[j], zs[j]);
                w[3][j] = fmaf((float)( qsB[j]       & 0xF), ss[j], zs[j]);
            }
#pragma unroll
            for (int b = 0; b < 8; ++b) {
                const float4 xb = *(const float4*)(x_lds + b * KC + i);
#pragma unroll
                for (int r = 0; r < 4; ++r) {
                    float a = acc[r][b];
                    a = fmaf(xb.x, w[r][0], a);
                    a = fmaf(xb.y, w[r][1], a);
                    a = fmaf(xb.z, w[r][2], a);
                    a = fmaf(xb.w, w[r][3], a);
                    acc[r][b] = a;
                }
            }
        }

        // ---- per-wave transpose reduce: NO barrier (same-wave ds order) ----
        // round m: write rows b (col lane^(b<<2): permutation, conflict-free);
        // read row ro=lane>>3, col-octet (lane&7)*8; 3-level shfl_xor.
#pragma unroll
        for (int m = 0; m < 4; ++m) {
#pragma unroll
            for (int b = 0; b < 8; ++b)
                red[b * 64 + (lane ^ (b << 2))] = acc[m][b];
            const int ro = lane >> 3;
            const int c0 = (lane & 7) * 8;
            const float4 u0 = *(const float4*)(red + ro * 64 + ((c0    ) ^ (ro << 2)));
            const float4 u1 = *(const float4*)(red + ro * 64 + ((c0 + 4) ^ (ro << 2)));
            float v = ((u0.x + u0.y) + (u0.z + u0.w)) +
                      ((u1.x + u1.y) + (u1.z + u1.w));
            v += __shfl_xor(v, 1, 64);
            v += __shfl_xor(v, 2, 64);
            v += __shfl_xor(v, 4, 64);
            if ((lane & 7) == 0)               // 8 lanes -> 32 B coalesced
                ws[(long)(((bx * OC_ + oc) * KS + ks) << 7) + ty * 32 + m * 8 + ro] = v;
        }
    }
}

__global__ void hqq_reduce(const float* __restrict__ ws,
                           const float* __restrict__ bias,
                           float* __restrict__ out) {
    // thread t = ws slot (c, o): reads coalesced, scatter on the store side.
    const int t = blockIdx.x * 256 + threadIdx.x;  // 0 .. 688*128-1 = 88063
    if (t >= 688 * 128) return;
    const int c = t >> 7;                      // chunk = bx*OC_ + oc, 0..687
    const int o = t & 127;                     // o = ty*32 + m*8 + b
    float v = 0.f;
#pragma unroll
    for (int k = 0; k < KS; ++k) v += ws[((long)c << 10) + (k << 7) + o];
    const int bx = c / OC_;
    const int oc = c % OC_;
    const int w_ = o >> 5;
    const int m  = (o >> 3) & 3;
    const int b  = o & 7;
    const int rq  = bx * 8 + w_ * 2 + (m >> 1);
    const int row = rq + ((m & 1) ? 32 : 0);
    const int oo  = row * OC_ + oc;
    out[b * OUT_ + oo] = v + bias[oo];
}

extern "C" void kernel_launch(void* const* d_in, const int* in_sizes, int n_in,
                              void* d_out, int out_size, void* d_ws, size_t ws_size,
                              hipStream_t stream) {
    const int*   Wq    = (const int*)d_in[0];    // [32, 704512] int32
    const float* scale = (const float*)d_in[1];  // [1, 704512]
    const float* zero  = (const float*)d_in[2];  // [1, 704512]
    const float* x     = (const float*)d_in[3];  // [8, 1, 4096]
    const float* bias  = (const float*)d_in[4];  // [11008]
    float* out = (float*)d_out;                  // [8, 1, 11008]
    float* ws  = (float*)d_ws;                   // 688*8*128 floats = 2.75 MB

    dim3 grid(NB);          // 1376 four-step blocks, XCD-chunked
    dim3 block(64, 4);
    hqq_gemv<<<grid, block, 0, stream>>>(Wq, scale, zero, x, ws);
    hqq_reduce<<<(688 * 128 + 255) / 256, 256, 0, stream>>>(ws, bias, out);
}

// Round 9
// 144.876 us; speedup vs baseline: 2.6863x; 1.2568x over previous
//
#include <hip/hip_runtime.h>

// HQQ 4-bit dequant + linear (Llama-7B up-proj, decode: 8 tokens)
// OUT=11008, IN=4096, GS=64, G=704512, OC=172 (=G/IN; OUT=64*OC)
// W_q: [32, G] int32 (one byte per word: hi nibble -> unpacked row rq,
//      lo nibble -> row rq+32 of the [64, G] tensor)
// Mapping: W_r[o, i] with r=o/172, oc=o%172, g=oc*4096+i.
//
// R12 = R5 restored verbatim (measured best: 144.3 us).
// Post-mortem of the pipeline family (R9/R10/R11): hipcc allocates VGPRs
// conservatively (64 reported under a 128 cap) and spills multi-buffer
// ping-pongs to scratch rather than using the launch-bounds budget; the
// scratch round-trip lands on the inner-loop critical path (R11: gemv
// 74 us @ 1.08 TB/s, 18 MB scratch writes). One-shot prefetch that FITS
// (R5: 32 VGPR of Wq) is the allocator-stable optimum.
// R5 anatomy: 4-wave block, s/z/x staged via global_load_lds width=16
// (async DMA, no VGPR round-trip), Wq prefetched to registers, one
// __syncthreads, unrolled FMA loop, XOR-swizzled LDS transpose reduce,
// coalesced 128-float ws store; separate reduce kernel adds bias.

#define OUT_ 11008
#define IN_ 4096
#define G_ 704512
#define OC_ 172
#define KS 4
#define KC (IN_ / KS)      // 1024
#define ITERS (KC / 256)   // 4
#define SIB (OC_ * KS)     // 688; 688%8==0 so bx-siblings land on same XCD
#define NB (4 * SIB)       // 2752 blocks

typedef const __attribute__((address_space(1))) void* gptr1_t;
typedef __attribute__((address_space(3))) void* sptr3_t;

__device__ __forceinline__ void gload_lds16(const float* g, float* l) {
    // dest is wave-uniform; HW adds lane*16B. src is per-lane.
    __builtin_amdgcn_global_load_lds((gptr1_t)g, (sptr3_t)l, 16, 0, 0);
}

__global__ __launch_bounds__(256, 4)
void hqq_gemv(const int* __restrict__ Wq, const float* __restrict__ scale,
              const float* __restrict__ zero, const float* __restrict__ x,
              float* __restrict__ ws) {
    __shared__ float x_lds[8 * KC];   // 32 KB; reused as red[128*64] at tail
    __shared__ float s_lds[KC];       // 4 KB
    __shared__ float z_lds[KC];       // 4 KB

    const int lane = threadIdx.x;              // 0..63
    const int ty   = threadIdx.y;              // 0..3
    const int tid  = ty * 64 + lane;
    const int bid  = blockIdx.x;
    const int bx   = bid / SIB;                // 0..3  (rq-group of 8 rows)
    const int rem  = bid % SIB;
    const int oc   = rem >> 2;                 // 0..171
    const int ks   = rem & 3;                  // 0..3
    const int rq0  = bx * 8 + ty * 2;          // packed rows rq0, rq0+1

    const int kbase = ks * KC;
    const int gb = oc * IN_ + kbase;

    // ---- async-stage s, z, x into LDS (wave-uniform dest, per-lane src) ----
    const int wf = ty * 256;                   // wave's float offset per round
    gload_lds16(scale + gb + wf + lane * 4, s_lds + wf);
    gload_lds16(zero  + gb + wf + lane * 4, z_lds + wf);
#pragma unroll
    for (int r = 0; r < 8; ++r) {              // round r covers batch b=r
        gload_lds16(x + r * IN_ + kbase + wf + lane * 4, x_lds + r * 1024 + wf);
    }

    // ---- prefetch ALL Wq for this wave: 8 independent dwordx4 (32 VGPR) ----
    const int* __restrict__ wqA = Wq + (long)rq0 * G_ + gb;
    const int* __restrict__ wqB = wqA + G_;
    int4 qA[ITERS], qB[ITERS];
#pragma unroll
    for (int it = 0; it < ITERS; ++it) {
        qA[it] = *(const int4*)(wqA + it * 256 + lane * 4);
        qB[it] = *(const int4*)(wqB + it * 256 + lane * 4);
    }

    __syncthreads();  // drains vmcnt: LDS-DMA + Wq regs all resident

    // acc[0]=hi(rq0) acc[1]=lo(rq0) acc[2]=hi(rq0+1) acc[3]=lo(rq0+1)
    float acc[4][8];
#pragma unroll
    for (int r = 0; r < 4; ++r)
#pragma unroll
        for (int b = 0; b < 8; ++b) acc[r][b] = 0.f;

#pragma unroll
    for (int it = 0; it < ITERS; ++it) {
        const int i = it * 256 + lane * 4;
        const float4 s4 = *(const float4*)(s_lds + i);
        const float4 z4 = *(const float4*)(z_lds + i);
        const float ss[4] = {s4.x, s4.y, s4.z, s4.w};
        const float zs[4] = {-z4.x * s4.x, -z4.y * s4.y, -z4.z * s4.z, -z4.w * s4.w};
        const int qsA[4] = {qA[it].x, qA[it].y, qA[it].z, qA[it].w};
        const int qsB[4] = {qB[it].x, qB[it].y, qB[it].z, qB[it].w};

        float w[4][4];  // [hiA, loA, hiB, loB][j]
#pragma unroll
        for (int j = 0; j < 4; ++j) {
            w[0][j] = fmaf((float)((qsA[j] >> 4) & 0xF), ss[j], zs[j]);
            w[1][j] = fmaf((float)( qsA[j]       & 0xF), ss[j], zs[j]);
            w[2][j] = fmaf((float)((qsB[j] >> 4) & 0xF), ss[j], zs[j]);
            w[3][j] = fmaf((float)( qsB[j]       & 0xF), ss[j], zs[j]);
        }
#pragma unroll
        for (int b = 0; b < 8; ++b) {
            const float4 xb = *(const float4*)(x_lds + b * KC + i);
#pragma unroll
            for (int r = 0; r < 4; ++r) {
                float a = acc[r][b];
                a = fmaf(xb.x, w[r][0], a);
                a = fmaf(xb.y, w[r][1], a);
                a = fmaf(xb.z, w[r][2], a);
                a = fmaf(xb.w, w[r][3], a);
                acc[r][b] = a;
            }
        }
    }

    // ---- LDS transpose reduce over the 64 K-slice lanes ----
    // red row o holds acc values from all 64 lanes; write side is a lane
    // permutation (free); read side: slot = (j ^ (o&7)) -> all 8 slots.
    float* red = x_lds;                        // x no longer needed
    __syncthreads();
    const int obase = ty * 32;
#pragma unroll
    for (int r = 0; r < 4; ++r)
#pragma unroll
        for (int b = 0; b < 8; ++b) {
            const int o = obase + r * 8 + b;
            red[o * 64 + (lane ^ ((o & 7) << 2))] = acc[r][b];
        }
    __syncthreads();

    if (tid < 128) {
        const int o = tid;                     // o = w_*32 + r*8 + b
        const int c = (o & 7) << 2;
        float s = 0.f;
#pragma unroll
        for (int j = 0; j < 16; ++j) {
            const float4 v = *(const float4*)(red + o * 64 + ((j * 4) ^ c));
            s += (v.x + v.y) + (v.z + v.w);
        }
        // coalesced: this block's 128 partials are contiguous
        ws[(long)((bx * OC_ + oc) * KS + ks) * 128 + o] = s;
    }
}

__global__ void hqq_reduce(const float* __restrict__ ws,
                           const float* __restrict__ bias,
                           float* __restrict__ out) {
    const int t = blockIdx.x * 256 + threadIdx.x;
    if (t >= 8 * OUT_) return;
    const int o = t % OUT_;
    const int b = t / OUT_;
    const int row = o / OC_;                   // 0..63
    const int oc  = o % OC_;
    const int rq  = row & 31;                  // packed row
    const int hi  = row >> 5;                  // 0 = hi nibble rows, 1 = lo
    const int bx  = rq >> 3;
    const int w_  = (rq >> 1) & 3;
    const int r   = ((rq & 1) << 1) | hi;
    const int base = ((bx * OC_ + oc) * KS) * 128 + w_ * 32 + r * 8 + b;
    float v = bias[o];
#pragma unroll
    for (int k = 0; k < KS; ++k) v += ws[base + k * 128];
    out[t] = v;
}

extern "C" void kernel_launch(void* const* d_in, const int* in_sizes, int n_in,
                              void* d_out, int out_size, void* d_ws, size_t ws_size,
                              hipStream_t stream) {
    const int*   Wq    = (const int*)d_in[0];    // [32, 704512] int32
    const float* scale = (const float*)d_in[1];  // [1, 704512]
    const float* zero  = (const float*)d_in[2];  // [1, 704512]
    const float* x     = (const float*)d_in[3];  // [8, 1, 4096]
    const float* bias  = (const float*)d_in[4];  // [11008]
    float* out = (float*)d_out;                  // [8, 1, 11008]
    float* ws  = (float*)d_ws;                   // NB*128 floats = 1.38 MB

    dim3 grid(NB);          // 2752, XCD-aligned sibling groups
    dim3 block(64, 4);
    hqq_gemv<<<grid, block, 0, stream>>>(Wq, scale, zero, x, ws);
    hqq_reduce<<<(8 * OUT_ + 255) / 256, 256, 0, stream>>>(ws, bias, out);
}